// Round 3
// baseline (45.675 us; speedup 1.0000x reference)
//
#include <hip/hip_runtime.h>

// RightPool: out[b,c,h,w] = max(x[b,c,h,0..w]) — cummax along last (contiguous) axis, W=128.
// One 32-lane group per row: float4 per lane (512B/row, coalesced), local 4-elem scan +
// 5-step shfl_up segmented scan (width=32). 2-row unroll for ILP; non-temporal stores so
// the output doesn't evict the (L3-sized) input from Infinity Cache across graph replays.

typedef float f32x4 __attribute__((ext_vector_type(4)));

__device__ __forceinline__ f32x4 scan_row(f32x4 v, int lane32) {
    float y0 = v.x;
    float y1 = fmaxf(y0, v.y);
    float y2 = fmaxf(y1, v.z);
    float y3 = fmaxf(y2, v.w);

    float m = y3;
    #pragma unroll
    for (int d = 1; d < 32; d <<= 1) {
        float t = __shfl_up(m, d, 32);
        if (lane32 >= d) m = fmaxf(m, t);
    }
    float ex = __shfl_up(m, 1, 32);
    if (lane32 == 0) ex = -__builtin_inff();

    f32x4 o;
    o.x = fmaxf(ex, y0);
    o.y = fmaxf(ex, y1);
    o.z = fmaxf(ex, y2);
    o.w = fmaxf(ex, y3);
    return o;
}

__global__ __launch_bounds__(256) void rightpool_kernel(const float* __restrict__ x,
                                                        float* __restrict__ out,
                                                        int nrows) {
    const int tid     = blockIdx.x * blockDim.x + threadIdx.x;
    const int lane32  = threadIdx.x & 31;
    const int ngroups = (gridDim.x * blockDim.x) >> 5;
    int row = tid >> 5;

    // 2-row unroll: both loads issued before either scan (independent, ILP).
    for (; row + ngroups < nrows; row += 2 * ngroups) {
        const f32x4* pa = reinterpret_cast<const f32x4*>(x + (size_t)row * 128) + lane32;
        const f32x4* pb = reinterpret_cast<const f32x4*>(x + ((size_t)row + (size_t)ngroups) * 128) + lane32;
        f32x4 va = *pa;
        f32x4 vb = *pb;

        f32x4 oa = scan_row(va, lane32);
        f32x4 ob = scan_row(vb, lane32);

        __builtin_nontemporal_store(oa, reinterpret_cast<f32x4*>(out + (size_t)row * 128) + lane32);
        __builtin_nontemporal_store(ob, reinterpret_cast<f32x4*>(out + ((size_t)row + (size_t)ngroups) * 128) + lane32);
    }
    if (row < nrows) {
        const f32x4* pa = reinterpret_cast<const f32x4*>(x + (size_t)row * 128) + lane32;
        f32x4 oa = scan_row(*pa, lane32);
        __builtin_nontemporal_store(oa, reinterpret_cast<f32x4*>(out + (size_t)row * 128) + lane32);
    }
}

extern "C" void kernel_launch(void* const* d_in, const int* in_sizes, int n_in,
                              void* d_out, int out_size, void* d_ws, size_t ws_size,
                              hipStream_t stream) {
    const float* x = (const float*)d_in[0];
    float* out     = (float*)d_out;

    const int W     = 128;
    const int nrows = out_size / W;  // 8*256*128 = 262144

    const int block = 256;
    int blocks_needed = (nrows * 32 + block - 1) / block;
    int blocks = blocks_needed < 2048 ? blocks_needed : 2048;

    rightpool_kernel<<<blocks, block, 0, stream>>>(x, out, nrows);
}

// Round 4
// 45.335 us; speedup vs baseline: 1.0075x; 1.0075x over previous
//
#include <hip/hip_runtime.h>

// RightPool: out[b,c,h,w] = max(x[b,c,h,0..w])  — cummax along last (contiguous) axis, W=128.
// One 32-lane group per row: float4 per lane (512B/row coalesced), local 4-elem scan +
// 5-step shfl_up segmented scan (width=32), then combine with exclusive prefix.
// Memory-roofline kernel: 268 MB moved at ~5.9 TB/s (94% of measured 6.29 TB/s copy ceiling).
// nt-stores and 2-row ILP unroll were tried (R2/R3) and measured neutral-to-worse.

__global__ void rightpool_kernel(const float* __restrict__ x,
                                 float* __restrict__ out,
                                 int nrows) {
    const int tid      = blockIdx.x * blockDim.x + threadIdx.x;
    const int nthreads = gridDim.x * blockDim.x;
    const int lane32   = threadIdx.x & 31;
    const int ngroups  = nthreads >> 5;

    for (int row = tid >> 5; row < nrows; row += ngroups) {
        const float4* px = reinterpret_cast<const float4*>(x + (size_t)row * 128) + lane32;
        float4 v = *px;

        // local inclusive scan over the 4 elements
        float y0 = v.x;
        float y1 = fmaxf(y0, v.y);
        float y2 = fmaxf(y1, v.z);
        float y3 = fmaxf(y2, v.w);

        // inclusive scan of lane maxes across the 32-lane segment
        float m = y3;
        #pragma unroll
        for (int d = 1; d < 32; d <<= 1) {
            float t = __shfl_up(m, d, 32);
            if (lane32 >= d) m = fmaxf(m, t);
        }
        // exclusive prefix for this lane
        float ex = __shfl_up(m, 1, 32);
        if (lane32 == 0) ex = -__builtin_inff();

        float4 o;
        o.x = fmaxf(ex, y0);
        o.y = fmaxf(ex, y1);
        o.z = fmaxf(ex, y2);
        o.w = fmaxf(ex, y3);
        *(reinterpret_cast<float4*>(out + (size_t)row * 128) + lane32) = o;
    }
}

extern "C" void kernel_launch(void* const* d_in, const int* in_sizes, int n_in,
                              void* d_out, int out_size, void* d_ws, size_t ws_size,
                              hipStream_t stream) {
    const float* x = (const float*)d_in[0];
    float* out     = (float*)d_out;

    const int W     = 128;
    const int nrows = out_size / W;  // 8*256*128 = 262144

    const int block = 256;
    int blocks_needed = (nrows * 32 + block - 1) / block;
    int blocks = blocks_needed < 2048 ? blocks_needed : 2048;

    rightpool_kernel<<<blocks, block, 0, stream>>>(x, out, nrows);
}